// Round 2
// baseline (195.332 us; speedup 1.0000x reference)
//
#include <hip/hip_runtime.h>
#include <math.h>

// Problem constants
#define BB 4096      // batch
#define NE 8         // experts
#define NP 256       // patches
#define NK 16        // patch dim
#define NF 64        // filter size
#define ROW 4096     // NP*NK floats per batch row
#define NBLK 1024    // main-kernel blocks (4 rows each)

// ws float layout:
//   [0,256)    W[e][j][k]   (e*32 + j*16 + k)   W = sum_f ew[e, j*64+f, k]
//   [256,272)  Bsum[e][j]   (e*2 + j)
//   [272]      completion counter (int)
//   [288, 288 + NBLK*16)  partials: part[blk*16 + i], i<8 -> h_e sums, i>=8 -> m_e sums
#define WS_W   0
#define WS_B   256
#define WS_CNT 272
#define WS_P   288

__global__ __launch_bounds__(256) void prep_kernel(const float* __restrict__ ew,
                                                   const float* __restrict__ eb,
                                                   float* __restrict__ ws) {
    int t = threadIdx.x;  // 256 threads
    // W[e][j][k] = sum_f ew[e, j*64+f, k]
    int e = t >> 5, j = (t >> 4) & 1, k = t & 15;
    const float* base = ew + e * (128 * 16) + j * (64 * 16) + k;
    float s = 0.f;
#pragma unroll
    for (int f = 0; f < 64; ++f) s += base[f * 16];
    ws[WS_W + t] = s;
    if (t < 16) {
        int e2 = t >> 1, j2 = t & 1;
        const float* bb = eb + e2 * 128 + j2 * 64;
        float sb = 0.f;
#pragma unroll
        for (int f = 0; f < 64; ++f) sb += bb[f];
        ws[WS_B + t] = sb;
    }
    if (t == 0) *(int*)(ws + WS_CNT) = 0;  // completion counter, re-zeroed every call
}

__global__ __launch_bounds__(256) void fused_kernel(const float* __restrict__ x,
                                                    const float* __restrict__ noise,
                                                    const float* __restrict__ gw,
                                                    const float* __restrict__ gb,
                                                    float* __restrict__ ws,
                                                    float* __restrict__ out) {
    __shared__ float hacc[8];
    __shared__ float macc[8];
    __shared__ int lastflag;
    int tid = threadIdx.x;
    if (tid < 8) { hacc[tid] = 0.f; macc[tid] = 0.f; }
    if (tid == 0) lastflag = 0;
    __syncthreads();

    int wave = tid >> 6;
    int lane = tid & 63;
    int b = blockIdx.x * 4 + wave;

    // --- row reduction: s[b,k] = sum_p x[b, p*16+k] ---
    const float4* xb = (const float4*)(x + (size_t)b * ROW);
    float4 acc = make_float4(0.f, 0.f, 0.f, 0.f);
#pragma unroll
    for (int t = 0; t < 16; ++t) {
        float4 v = xb[lane + 64 * t];
        acc.x += v.x; acc.y += v.y; acc.z += v.z; acc.w += v.w;
    }
    // lanes sharing (lane&3) reduce together; afterwards lane q in {0..3}
    // holds buckets {4q..4q+3} (as does every lane with lane&3==q)
#pragma unroll
    for (int m = 4; m <= 32; m <<= 1) {
        acc.x += __shfl_xor(acc.x, m);
        acc.y += __shfl_xor(acc.y, m);
        acc.z += __shfl_xor(acc.z, m);
        acc.w += __shfl_xor(acc.w, m);
    }
    // broadcast all 16 bucket sums to every lane (no LDS needed)
    float s[16];
#pragma unroll
    for (int q = 0; q < 4; ++q) {
        s[4 * q + 0] = __shfl(acc.x, q);
        s[4 * q + 1] = __shfl(acc.y, q);
        s[4 * q + 2] = __shfl(acc.z, q);
        s[4 * q + 3] = __shfl(acc.w, q);
    }

    // --- gating: lanes 0..7 compute h[b,e] for e=lane ---
    float hv = -3.0e38f;
    if (lane < 8) {
        const float* gwr = gw + lane * NK;
        float d = 0.f;
#pragma unroll
        for (int k = 0; k < NK; ++k) d += s[k] * gwr[k];
        hv = d + 256.f * gb[lane] + noise[b];
    }
    // argmax (first-index tie-break) across lanes 0..7
    float mv = hv;
    int mi = lane & 7;
#pragma unroll
    for (int m = 1; m <= 4; m <<= 1) {
        float ov = __shfl_xor(mv, m);
        int oi = __shfl_xor(mi, m);
        if (ov > mv || (ov == mv && oi < mi)) { mv = ov; mi = oi; }
    }
    // lanes 0..7 now hold pi_val=mv, e*=mi

    if (lane == 0) {
        const float* Wr = ws + WS_W + mi * 32;
        const float* Bs = ws + WS_B + mi * 2;
        float o0 = 0.f, o1 = 0.f;
#pragma unroll
        for (int k = 0; k < NK; ++k) {
            float sv = s[k];
            o0 += sv * Wr[k];
            o1 += sv * Wr[16 + k];
        }
        out[b * 2 + 0] = mv * (o0 + 256.f * Bs[0]);
        out[b * 2 + 1] = mv * (o1 + 256.f * Bs[1]);
    }
    if (lane < 8) {
        float mk = (lane == mi) ? 1.f : 0.f;
        out[2 * BB + b * 8 + lane] = mk;   // mask output
        atomicAdd(&hacc[lane], hv);
        atomicAdd(&macc[lane], mk);
    }
    __syncthreads();

    // --- per-block partials -> ws, device-visible (cross-XCD safe) ---
    float* part = ws + WS_P;
    if (tid < 8) {
        __hip_atomic_store(&part[blockIdx.x * 16 + tid], hacc[tid],
                           __ATOMIC_RELEASE, __HIP_MEMORY_SCOPE_AGENT);
    } else if (tid < 16) {
        __hip_atomic_store(&part[blockIdx.x * 16 + tid], macc[tid - 8],
                           __ATOMIC_RELEASE, __HIP_MEMORY_SCOPE_AGENT);
    }
    __syncthreads();
    if (tid == 0) {
        __threadfence();
        int old = atomicAdd((int*)(ws + WS_CNT), 1);
        if (old == NBLK - 1) lastflag = 1;
    }
    __syncthreads();

    // --- last block computes the loss ---
    if (lastflag) {
        __shared__ float red[16][17];
        int e = tid & 15, c = tid >> 4;  // 16 chunks of 64 blocks
        float sum = 0.f;
        for (int blk = c; blk < NBLK; blk += 16)
            sum += __hip_atomic_load(&part[blk * 16 + e],
                                     __ATOMIC_ACQUIRE, __HIP_MEMORY_SCOPE_AGENT);
        red[c][e] = sum;
        __syncthreads();
        if (tid == 0) {
            float hs[8], ms[8];
#pragma unroll
            for (int e2 = 0; e2 < 8; ++e2) { hs[e2] = 0.f; ms[e2] = 0.f; }
            for (int c2 = 0; c2 < 16; ++c2) {
#pragma unroll
                for (int e2 = 0; e2 < 8; ++e2) {
                    hs[e2] += red[c2][e2];
                    ms[e2] += red[c2][8 + e2];
                }
            }
            float loss = 0.f;
#pragma unroll
            for (int e2 = 0; e2 < 8; ++e2)
                loss += (hs[e2] / 4096.f) * (ms[e2] / 4096.f);
            out[2 * BB + 8 * BB] = loss * 8.f;  // index 40960
        }
    }
}

extern "C" void kernel_launch(void* const* d_in, const int* in_sizes, int n_in,
                              void* d_out, int out_size, void* d_ws, size_t ws_size,
                              hipStream_t stream) {
    const float* x     = (const float*)d_in[0];
    const float* noise = (const float*)d_in[1];
    const float* gw    = (const float*)d_in[2];
    const float* gb    = (const float*)d_in[3];
    const float* ew    = (const float*)d_in[4];
    const float* eb    = (const float*)d_in[5];
    float* out = (float*)d_out;
    float* ws  = (float*)d_ws;

    prep_kernel<<<1, 256, 0, stream>>>(ew, eb, ws);
    fused_kernel<<<NBLK, 256, 0, stream>>>(x, noise, gw, gb, ws, out);
}

// Round 3
// 123.646 us; speedup vs baseline: 1.5798x; 1.5798x over previous
//
#include <hip/hip_runtime.h>
#include <math.h>

// Problem constants
#define BB 4096      // batch
#define NE 8         // experts
#define NP 256       // patches
#define NK 16        // patch dim
#define NF 64        // filter size
#define ROW 4096     // NP*NK floats per batch row
#define NBLK 1024    // main-kernel blocks (4 rows each)

// ws float layout:
//   [0,256)          W[e][j][k]  (e*32 + j*16 + k)   W = sum_f ew[e, j*64+f, k]
//   [256,272)        Bsum[e][j]  (e*2 + j)
//   [272, 272+8192)  hpart[block][e]   (1024 blocks)
//   [8464, 16656)    mpart[block][e]
#define WS_W 0
#define WS_B 256
#define WS_H 272
#define WS_M 8464

__global__ __launch_bounds__(256) void prep_kernel(const float* __restrict__ ew,
                                                   const float* __restrict__ eb,
                                                   float* __restrict__ ws) {
    int t = threadIdx.x;  // 256 threads
    // W[e][j][k] = sum_f ew[e, j*64+f, k]
    int e = t >> 5, j = (t >> 4) & 1, k = t & 15;
    const float* base = ew + e * (128 * 16) + j * (64 * 16) + k;
    float s = 0.f;
#pragma unroll
    for (int f = 0; f < 64; ++f) s += base[f * 16];
    ws[WS_W + t] = s;
    if (t < 16) {
        int e2 = t >> 1, j2 = t & 1;
        const float* bb = eb + e2 * 128 + j2 * 64;
        float sb = 0.f;
#pragma unroll
        for (int f = 0; f < 64; ++f) sb += bb[f];
        ws[WS_B + t] = sb;
    }
}

// 4 waves/block, one batch row per wave. __launch_bounds__(256,4): 4 waves/EU
// floor -> VGPR cap 128, enough for the 16-deep float4 load pipeline below
// (R2's 52-VGPR build kept only ~5 loads in flight -> 90us latency-bound).
__global__ __launch_bounds__(256, 4) void main_kernel(const float* __restrict__ x,
                                                      const float* __restrict__ noise,
                                                      const float* __restrict__ gw,
                                                      const float* __restrict__ gb,
                                                      const float* __restrict__ ws,
                                                      float* __restrict__ out,
                                                      float* __restrict__ hpart,
                                                      float* __restrict__ mpart) {
    __shared__ float hacc[8];
    __shared__ float macc[8];
    int tid = threadIdx.x;
    if (tid < 8) { hacc[tid] = 0.f; macc[tid] = 0.f; }
    __syncthreads();

    int wave = tid >> 6;
    int lane = tid & 63;
    int b = blockIdx.x * 4 + wave;

    // --- row reduction: s[b,k] = sum_p x[b, p*16+k] ---
    // Load the whole 16KB row (16 float4/lane) into registers FIRST, so all
    // 16 global loads are outstanding simultaneously, then tree-reduce.
    const float4* xb = (const float4*)(x + (size_t)b * ROW);
    float4 v[16];
#pragma unroll
    for (int t = 0; t < 16; ++t) v[t] = xb[lane + 64 * t];
#pragma unroll
    for (int st = 8; st >= 1; st >>= 1) {
#pragma unroll
        for (int t = 0; t < st; ++t) {
            v[t].x += v[t + st].x; v[t].y += v[t + st].y;
            v[t].z += v[t + st].z; v[t].w += v[t + st].w;
        }
    }
    float4 acc = v[0];
    // lanes sharing (lane&3) hold the same 4 buckets; butterfly-reduce them
#pragma unroll
    for (int m = 4; m <= 32; m <<= 1) {
        acc.x += __shfl_xor(acc.x, m);
        acc.y += __shfl_xor(acc.y, m);
        acc.z += __shfl_xor(acc.z, m);
        acc.w += __shfl_xor(acc.w, m);
    }
    // broadcast all 16 bucket sums to every lane (lane q<4 holds buckets 4q..4q+3)
    float s[16];
#pragma unroll
    for (int q = 0; q < 4; ++q) {
        s[4 * q + 0] = __shfl(acc.x, q);
        s[4 * q + 1] = __shfl(acc.y, q);
        s[4 * q + 2] = __shfl(acc.z, q);
        s[4 * q + 3] = __shfl(acc.w, q);
    }

    // --- gating: lanes 0..7 compute h[b,e] for e=lane ---
    float hv = -3.0e38f;
    if (lane < 8) {
        const float* gwr = gw + lane * NK;
        float d = 0.f;
#pragma unroll
        for (int k = 0; k < NK; ++k) d += s[k] * gwr[k];
        hv = d + 256.f * gb[lane] + noise[b];
    }
    // argmax (first-index tie-break) across lanes 0..7
    float mv = hv;
    int mi = lane & 7;
#pragma unroll
    for (int m = 1; m <= 4; m <<= 1) {
        float ov = __shfl_xor(mv, m);
        int oi = __shfl_xor(mi, m);
        if (ov > mv || (ov == mv && oi < mi)) { mv = ov; mi = oi; }
    }
    // lanes 0..7 now hold pi_val=mv, e*=mi

    if (lane == 0) {
        const float* Wr = ws + WS_W + mi * 32;
        const float* Bs = ws + WS_B + mi * 2;
        float o0 = 0.f, o1 = 0.f;
#pragma unroll
        for (int k = 0; k < NK; ++k) {
            float sv = s[k];
            o0 += sv * Wr[k];
            o1 += sv * Wr[16 + k];
        }
        out[b * 2 + 0] = mv * (o0 + 256.f * Bs[0]);
        out[b * 2 + 1] = mv * (o1 + 256.f * Bs[1]);
    }
    if (lane < 8) {
        float mk = (lane == mi) ? 1.f : 0.f;
        out[2 * BB + b * 8 + lane] = mk;   // mask output
        atomicAdd(&hacc[lane], hv);
        atomicAdd(&macc[lane], mk);
    }
    __syncthreads();
    // plain stores; the loss kernel runs in a later dispatch, and end-of-kernel
    // release makes these visible device-wide (no per-block fences -- R2's
    // agent-scope fences cost ~50us in per-XCD L2 writebacks)
    if (tid < 8) {
        hpart[blockIdx.x * 8 + tid] = hacc[tid];
        mpart[blockIdx.x * 8 + tid] = macc[tid];
    }
}

__global__ __launch_bounds__(256) void loss_kernel(const float* __restrict__ hpart,
                                                   const float* __restrict__ mpart,
                                                   float* __restrict__ out) {
    __shared__ float hs[256], ms[256];
    int t = threadIdx.x;
    int e = t & 7, c = t >> 3;  // 32 chunks of 32 blocks
    float hsum = 0.f, msum = 0.f;
    for (int i = c; i < NBLK; i += 32) {
        hsum += hpart[i * 8 + e];
        msum += mpart[i * 8 + e];
    }
    hs[t] = hsum;
    ms[t] = msum;
    __syncthreads();
    if (t < 8) {
        float hh = 0.f, mm = 0.f;
        for (int c2 = 0; c2 < 32; ++c2) { hh += hs[c2 * 8 + t]; mm += ms[c2 * 8 + t]; }
        hs[t] = hh;
        ms[t] = mm;
    }
    __syncthreads();
    if (t == 0) {
        float loss = 0.f;
        for (int e2 = 0; e2 < 8; ++e2)
            loss += (hs[e2] / 4096.f) * (ms[e2] / 4096.f);
        out[2 * BB + 8 * BB] = loss * 8.f;  // index 40960
    }
}

extern "C" void kernel_launch(void* const* d_in, const int* in_sizes, int n_in,
                              void* d_out, int out_size, void* d_ws, size_t ws_size,
                              hipStream_t stream) {
    const float* x     = (const float*)d_in[0];
    const float* noise = (const float*)d_in[1];
    const float* gw    = (const float*)d_in[2];
    const float* gb    = (const float*)d_in[3];
    const float* ew    = (const float*)d_in[4];
    const float* eb    = (const float*)d_in[5];
    float* out = (float*)d_out;
    float* ws  = (float*)d_ws;

    prep_kernel<<<1, 256, 0, stream>>>(ew, eb, ws);
    main_kernel<<<NBLK, 256, 0, stream>>>(x, noise, gw, gb, ws, out,
                                          ws + WS_H, ws + WS_M);
    loss_kernel<<<1, 256, 0, stream>>>(ws + WS_H, ws + WS_M, out);
}

// Round 4
// 111.485 us; speedup vs baseline: 1.7521x; 1.1091x over previous
//
#include <hip/hip_runtime.h>
#include <math.h>

// Problem constants
#define BB 4096      // batch
#define NE 8         // experts
#define NP 256       // patches
#define NK 16        // patch dim
#define NF 64        // filter size
#define ROW 4096     // NP*NK floats per batch row
#define NBLK 1024    // main-kernel blocks (4 rows each)

// ws float layout:
//   [0, 8192)     hpart[block][e]   (1024 blocks x 8 experts)
//   [8192, 16384) mpart[block][e]
#define WS_H 0
#define WS_M 8192

// One batch row per wave, 4 waves/block. Gating sums, argmax, AND the expert
// output are all computed in-wave: o_j = sum_f(sum_k s_k ew[e*,jF+f,k]) needs
// only ew[e*] (8 KB; ew totals 512 KB -> L2/L3-resident), so no prep pass.
__global__ __launch_bounds__(256, 4) void main_kernel(const float* __restrict__ x,
                                                      const float* __restrict__ noise,
                                                      const float* __restrict__ gw,
                                                      const float* __restrict__ gb,
                                                      const float* __restrict__ ew,
                                                      const float* __restrict__ eb,
                                                      float* __restrict__ out,
                                                      float* __restrict__ hpart,
                                                      float* __restrict__ mpart) {
    __shared__ float hacc[8];
    __shared__ float macc[8];
    int tid = threadIdx.x;
    if (tid < 8) { hacc[tid] = 0.f; macc[tid] = 0.f; }
    __syncthreads();

    int wave = tid >> 6;
    int lane = tid & 63;
    int b = blockIdx.x * 4 + wave;

    // --- row reduction: s[b,k] = sum_p x[b, p*16+k] ---
    // All 16 float4 loads issued before any use -> 16 KB in flight per wave.
    const float4* xb = (const float4*)(x + (size_t)b * ROW);
    float4 v[16];
#pragma unroll
    for (int t = 0; t < 16; ++t) v[t] = xb[lane + 64 * t];
#pragma unroll
    for (int st = 8; st >= 1; st >>= 1) {
#pragma unroll
        for (int t = 0; t < st; ++t) {
            v[t].x += v[t + st].x; v[t].y += v[t + st].y;
            v[t].z += v[t + st].z; v[t].w += v[t + st].w;
        }
    }
    float4 acc = v[0];
    // lanes sharing (lane&3) hold the same 4 buckets; butterfly-reduce
#pragma unroll
    for (int m = 4; m <= 32; m <<= 1) {
        acc.x += __shfl_xor(acc.x, m);
        acc.y += __shfl_xor(acc.y, m);
        acc.z += __shfl_xor(acc.z, m);
        acc.w += __shfl_xor(acc.w, m);
    }
    // broadcast all 16 bucket sums to every lane (lane q<4 holds buckets 4q..4q+3)
    float s[16];
#pragma unroll
    for (int q = 0; q < 4; ++q) {
        s[4 * q + 0] = __shfl(acc.x, q);
        s[4 * q + 1] = __shfl(acc.y, q);
        s[4 * q + 2] = __shfl(acc.z, q);
        s[4 * q + 3] = __shfl(acc.w, q);
    }

    // --- gating: lanes 0..7 compute h[b,e] for e=lane ---
    float hv = -3.0e38f;
    if (lane < 8) {
        const float* gwr = gw + lane * NK;
        float d = 0.f;
#pragma unroll
        for (int k = 0; k < NK; ++k) d += s[k] * gwr[k];
        hv = d + 256.f * gb[lane] + noise[b];
    }
    // argmax (first-index tie-break) within lanes 0..7
    float mv = hv;
    int mi = lane & 7;
#pragma unroll
    for (int m = 1; m <= 4; m <<= 1) {
        float ov = __shfl_xor(mv, m);
        int oi = __shfl_xor(mi, m);
        if (ov > mv || (ov == mv && oi < mi)) { mv = ov; mi = oi; }
    }
    // broadcast winner to all 64 lanes
    mv = __shfl(mv, 0);
    mi = __shfl(mi, 0);

    // --- expert output, computed in-wave from ew[mi] (L2-hot) ---
    // lane l handles channel l (j=0 half) and channel 64+l (j=1 half):
    //   dot_j = sum_k s[k] * ew[mi, jF+l, k]
    const float4* ewr = (const float4*)(ew + (size_t)mi * (128 * 16));
    float4 c0[4], c1[4];
#pragma unroll
    for (int q = 0; q < 4; ++q) {
        c0[q] = ewr[lane * 4 + q];          // channel lane,    k = 4q..4q+3
        c1[q] = ewr[(64 + lane) * 4 + q];   // channel 64+lane
    }
    float o0 = 0.f, o1 = 0.f;
#pragma unroll
    for (int q = 0; q < 4; ++q) {
        o0 += s[4*q+0]*c0[q].x + s[4*q+1]*c0[q].y + s[4*q+2]*c0[q].z + s[4*q+3]*c0[q].w;
        o1 += s[4*q+0]*c1[q].x + s[4*q+1]*c1[q].y + s[4*q+2]*c1[q].z + s[4*q+3]*c1[q].w;
    }
    // fold bias: each of the 64 f-positions contributes 256*eb once
    o0 += 256.f * eb[mi * 128 + lane];
    o1 += 256.f * eb[mi * 128 + 64 + lane];
    // butterfly sum both halves across the wave
#pragma unroll
    for (int m = 1; m <= 32; m <<= 1) {
        o0 += __shfl_xor(o0, m);
        o1 += __shfl_xor(o1, m);
    }
    if (lane == 0) {
        out[b * 2 + 0] = mv * o0;
        out[b * 2 + 1] = mv * o1;
    }

    if (lane < 8) {
        float mk = (lane == mi) ? 1.f : 0.f;
        out[2 * BB + b * 8 + lane] = mk;   // mask output
        atomicAdd(&hacc[lane], hv);
        atomicAdd(&macc[lane], mk);
    }
    __syncthreads();
    // plain stores; loss kernel is a later dispatch -> end-of-kernel release
    // gives device-wide visibility without per-block fences (R2 lesson)
    if (tid < 8) {
        hpart[blockIdx.x * 8 + tid] = hacc[tid];
        mpart[blockIdx.x * 8 + tid] = macc[tid];
    }
}

__global__ __launch_bounds__(256) void loss_kernel(const float* __restrict__ hpart,
                                                   const float* __restrict__ mpart,
                                                   float* __restrict__ out) {
    __shared__ float hs[256], ms[256];
    int t = threadIdx.x;
    int e = t & 7, c = t >> 3;  // 32 chunks of 32 blocks
    float hsum = 0.f, msum = 0.f;
    for (int i = c; i < NBLK; i += 32) {
        hsum += hpart[i * 8 + e];
        msum += mpart[i * 8 + e];
    }
    hs[t] = hsum;
    ms[t] = msum;
    __syncthreads();
    if (t < 8) {
        float hh = 0.f, mm = 0.f;
        for (int c2 = 0; c2 < 32; ++c2) { hh += hs[c2 * 8 + t]; mm += ms[c2 * 8 + t]; }
        hs[t] = hh;
        ms[t] = mm;
    }
    __syncthreads();
    if (t == 0) {
        float loss = 0.f;
        for (int e2 = 0; e2 < 8; ++e2)
            loss += (hs[e2] / 4096.f) * (ms[e2] / 4096.f);
        out[2 * BB + 8 * BB] = loss * 8.f;  // index 40960
    }
}

extern "C" void kernel_launch(void* const* d_in, const int* in_sizes, int n_in,
                              void* d_out, int out_size, void* d_ws, size_t ws_size,
                              hipStream_t stream) {
    const float* x     = (const float*)d_in[0];
    const float* noise = (const float*)d_in[1];
    const float* gw    = (const float*)d_in[2];
    const float* gb    = (const float*)d_in[3];
    const float* ew    = (const float*)d_in[4];
    const float* eb    = (const float*)d_in[5];
    float* out = (float*)d_out;
    float* ws  = (float*)d_ws;

    main_kernel<<<NBLK, 256, 0, stream>>>(x, noise, gw, gb, ew, eb, out,
                                          ws + WS_H, ws + WS_M);
    loss_kernel<<<1, 256, 0, stream>>>(ws + WS_H, ws + WS_M, out);
}